// Round 1
// baseline (953.628 us; speedup 1.0000x reference)
//
#include <hip/hip_runtime.h>
#include <cstdint>
#include <cstddef>

// Problem constants (from reference): N=50000 nodes, E=500000 edges, EMB=64,
// PRED_IN=276.  h_e = [x(64) | topic(2) | f1(2) | f2(2) | r1(2) | r2(2)] = 74,
// padded to 76 floats per row for 16B alignment.

// ---------------------------------------------------------------------------
// Prep kernels
// ---------------------------------------------------------------------------

// Detect whether edge_index is stored as int64 (odd int32 words all zero) or
// int32. flag=1 -> int32 storage, flag=0 -> int64 storage.
__global__ void k_detect(const int* __restrict__ idx, int E, int* __restrict__ flag) {
    int e = blockIdx.x * blockDim.x + threadIdx.x;
    bool nz = (e < E) && (idx[2 * e + 1] != 0);   // 2e+1 < 2E: in-bounds either way
    unsigned long long m = __ballot(nz);
    if (m != 0ull && (threadIdx.x & 63) == 0) atomicOr(flag, 1);
}

__global__ void k_convert(const int* __restrict__ idx, int E, const int* __restrict__ flag,
                          int* __restrict__ src_i, int* __restrict__ dst_i) {
    int e = blockIdx.x * blockDim.x + threadIdx.x;
    if (e >= E) return;
    if (*flag) {                      // int32 storage: [src[E] | dst[E]]
        src_i[e] = idx[e];
        dst_i[e] = idx[E + e];
    } else {                          // int64 storage: low words at even positions
        src_i[e] = idx[2 * e];
        dst_i[e] = idx[2 * E + 2 * e];
    }
}

__global__ void k_counts(const int* __restrict__ src_i, const int* __restrict__ dst_i,
                         float* __restrict__ deg_src, float* __restrict__ deg_dst, int E) {
    int e = blockIdx.x * blockDim.x + threadIdx.x;
    if (e >= E) return;
    atomicAdd(&deg_dst[dst_i[e]], 1.0f);
    atomicAdd(&deg_src[src_i[e]], 1.0f);
}

// out[seg[e]] += hin[gth[e]]  (2 floats per node)
__global__ void k_scatter(const float* __restrict__ hin, const int* __restrict__ gth,
                          const int* __restrict__ seg, float* __restrict__ out, int E) {
    int e = blockIdx.x * blockDim.x + threadIdx.x;
    if (e >= E) return;
    int g = gth[e], s = seg[e];
    float a = hin[2 * g], b = hin[2 * g + 1];
    atomicAdd(&out[2 * s], a);
    atomicAdd(&out[2 * s + 1], b);
}

__global__ void k_div(float* __restrict__ buf, const float* __restrict__ deg, int N) {
    int n = blockIdx.x * blockDim.x + threadIdx.x;
    if (n >= N) return;
    float c = fmaxf(deg[n], 1.0f);
    buf[2 * n]     /= c;
    buf[2 * n + 1] /= c;
}

// Build h_e[n][76]: x (with zero-row -> non_text_emb), topic, f1, f2, r1, r2, pad.
__global__ void k_build(const float* __restrict__ x, const float* __restrict__ topic,
                        const float* __restrict__ nte,
                        const float* __restrict__ f1, const float* __restrict__ f2,
                        const float* __restrict__ r1, const float* __restrict__ r2,
                        float* __restrict__ h_e, int N) {
    int n = blockIdx.x * blockDim.x + threadIdx.x;
    if (n >= N) return;
    const float4* xr = (const float4*)(x + (size_t)n * 64);
    float4 v[16];
    bool allz = true;
#pragma unroll
    for (int i = 0; i < 16; ++i) {
        v[i] = xr[i];
        allz = allz && (v[i].x == 0.f && v[i].y == 0.f && v[i].z == 0.f && v[i].w == 0.f);
    }
    const float4* nr = (const float4*)nte;
    float4* hr = (float4*)(h_e + (size_t)n * 76);
#pragma unroll
    for (int i = 0; i < 16; ++i) hr[i] = allz ? nr[i] : v[i];
    float* t = h_e + (size_t)n * 76;
    t[64] = topic[2 * n];  t[65] = topic[2 * n + 1];
    t[66] = f1[2 * n];     t[67] = f1[2 * n + 1];
    t[68] = f2[2 * n];     t[69] = f2[2 * n + 1];
    t[70] = r1[2 * n];     t[71] = r1[2 * n + 1];
    t[72] = r2[2 * n];     t[73] = r2[2 * n + 1];
    t[74] = 0.f;           t[75] = 0.f;
}

// ---------------------------------------------------------------------------
// Main fused MLP kernel: per-edge [q_emb | h_e[src] | edge_attr | h_e[dst]] @ W1
// -> relu -> @ W2.  W1 staged per-segment in LDS (broadcast reads).
// ---------------------------------------------------------------------------

__device__ __forceinline__ void stage_and_compute(
    float* __restrict__ Ws, const float* __restrict__ W1,
    int ko, int Lk, int Lp, int tid,
    const float4* __restrict__ r0, const float4* __restrict__ r1,
    float* __restrict__ acc0, float* __restrict__ acc1)
{
    __syncthreads();                       // previous segment done with Ws
    const int tot = Lp * 64;
    for (int i = tid; i < tot; i += 256) {
        int kk = i >> 6;
        Ws[i] = (kk < Lk) ? W1[(ko + kk) * 64 + (i & 63)] : 0.f;
    }
    __syncthreads();
    const int L4 = Lp >> 2;
#pragma unroll 1
    for (int kk4 = 0; kk4 < L4; ++kk4) {
        float4 a0 = r0[kk4];
        float4 a1 = r1[kk4];
        const float* wb = Ws + kk4 * 256;
#pragma unroll
        for (int u = 0; u < 4; ++u) {
            const float a0u = (u == 0) ? a0.x : (u == 1) ? a0.y : (u == 2) ? a0.z : a0.w;
            const float a1u = (u == 0) ? a1.x : (u == 1) ? a1.y : (u == 2) ? a1.z : a1.w;
            const float4* wrow = (const float4*)(wb + u * 64);
#pragma unroll
            for (int j4 = 0; j4 < 16; ++j4) {
                float4 w = wrow[j4];
                const int j = j4 * 4;
                acc0[j + 0] = fmaf(a0u, w.x, acc0[j + 0]);
                acc0[j + 1] = fmaf(a0u, w.y, acc0[j + 1]);
                acc0[j + 2] = fmaf(a0u, w.z, acc0[j + 2]);
                acc0[j + 3] = fmaf(a0u, w.w, acc0[j + 3]);
                acc1[j + 0] = fmaf(a1u, w.x, acc1[j + 0]);
                acc1[j + 1] = fmaf(a1u, w.y, acc1[j + 1]);
                acc1[j + 2] = fmaf(a1u, w.z, acc1[j + 2]);
                acc1[j + 3] = fmaf(a1u, w.w, acc1[j + 3]);
            }
        }
    }
}

__launch_bounds__(256, 2)
__global__ void k_gemm(const float* __restrict__ q_emb,
                       const float* __restrict__ edge_attr,
                       const float* __restrict__ h_e,
                       const int* __restrict__ src_i,
                       const int* __restrict__ dst_i,
                       const float* __restrict__ W1,
                       const float* __restrict__ b1,
                       const float* __restrict__ W2,
                       const float* __restrict__ b2,
                       float* __restrict__ out, int E)
{
    __shared__ float Ws[76 * 64];    // 19456 B, one W1 segment (zero-padded)
    __shared__ float b1s[64];
    __shared__ float W2s[64];
    const int tid = threadIdx.x;
    const int e0 = blockIdx.x * 512 + tid;
    const int e1 = e0 + 256;
    const bool v0 = e0 < E, v1 = e1 < E;
    const int ce0 = v0 ? e0 : 0;
    const int ce1 = v1 ? e1 : 0;
    const int s0 = src_i[ce0], d0 = dst_i[ce0];
    const int s1 = src_i[ce1], d1 = dst_i[ce1];
    if (tid < 64) { b1s[tid] = b1[tid]; W2s[tid] = W2[tid]; }

    float acc0[64], acc1[64];
#pragma unroll
    for (int j = 0; j < 64; ++j) { acc0[j] = 0.f; acc1[j] = 0.f; }

    const float4* g0a = (const float4*)(q_emb     + (size_t)ce0 * 64);
    const float4* g0b = (const float4*)(q_emb     + (size_t)ce1 * 64);
    const float4* g1a = (const float4*)(h_e       + (size_t)s0  * 76);
    const float4* g1b = (const float4*)(h_e       + (size_t)s1  * 76);
    const float4* g2a = (const float4*)(edge_attr + (size_t)ce0 * 64);
    const float4* g2b = (const float4*)(edge_attr + (size_t)ce1 * 64);
    const float4* g3a = (const float4*)(h_e       + (size_t)d0  * 76);
    const float4* g3b = (const float4*)(h_e       + (size_t)d1  * 76);

    // K segments: q[0,64) h_src[64,138) attr[138,202) h_dst[202,276)
    stage_and_compute(Ws, W1,   0, 64, 64, tid, g0a, g0b, acc0, acc1);
    stage_and_compute(Ws, W1,  64, 74, 76, tid, g1a, g1b, acc0, acc1);
    stage_and_compute(Ws, W1, 138, 64, 64, tid, g2a, g2b, acc0, acc1);
    stage_and_compute(Ws, W1, 202, 74, 76, tid, g3a, g3b, acc0, acc1);

    float o0 = b2[0], o1 = o0;
#pragma unroll
    for (int j = 0; j < 64; ++j) {
        float h0 = acc0[j] + b1s[j]; h0 = h0 > 0.f ? h0 : 0.f;
        float h1 = acc1[j] + b1s[j]; h1 = h1 > 0.f ? h1 : 0.f;
        o0 = fmaf(h0, W2s[j], o0);
        o1 = fmaf(h1, W2s[j], o1);
    }
    if (v0) out[e0] = o0;
    if (v1) out[e1] = o1;
}

// ---------------------------------------------------------------------------
// Launch
// ---------------------------------------------------------------------------

extern "C" void kernel_launch(void* const* d_in, const int* in_sizes, int n_in,
                              void* d_out, int out_size, void* d_ws, size_t ws_size,
                              hipStream_t stream)
{
    const float* x         = (const float*)d_in[0];
    const int*   eidx      = (const int*)  d_in[1];
    const float* edge_attr = (const float*)d_in[2];
    const float* topic     = (const float*)d_in[3];
    const float* q_emb     = (const float*)d_in[4];
    const float* nte       = (const float*)d_in[5];
    const float* W1        = (const float*)d_in[6];
    const float* b1        = (const float*)d_in[7];
    const float* W2        = (const float*)d_in[8];
    const float* b2        = (const float*)d_in[9];
    float* out = (float*)d_out;

    const int E = out_size;             // 500000
    const int N = in_sizes[0] / 64;     // 50000

    // Workspace layout (bytes):
    // [flag:16][deg_src:4N][deg_dst:4N][f1:8N][f2:8N][r1:8N][r2:8N][h_e:304N][src_i:4E][dst_i:4E]
    char* ws = (char*)d_ws;
    int*   flag    = (int*)ws;
    float* deg_src = (float*)(ws + 16);
    float* deg_dst = deg_src + N;
    float* f1  = deg_dst + N;
    float* f2  = f1 + 2 * (size_t)N;
    float* r1  = f2 + 2 * (size_t)N;
    float* r2  = r1 + 2 * (size_t)N;
    float* h_e = r2 + 2 * (size_t)N;
    int* src_i = (int*)(h_e + (size_t)N * 76);
    int* dst_i = src_i + E;

    size_t needed = 16 + (size_t)40 * N + (size_t)304 * N + (size_t)8 * E;
    if (ws_size < needed) return;   // avoid OOB scribbling if workspace too small

    size_t zero_bytes = 16 + (size_t)40 * N;   // flag + deg_src..r2
    hipMemsetAsync(d_ws, 0, zero_bytes, stream);

    const int gE = (E + 255) / 256;
    const int gN = (N + 255) / 256;

    k_detect <<<gE, 256, 0, stream>>>(eidx, E, flag);
    k_convert<<<gE, 256, 0, stream>>>(eidx, E, flag, src_i, dst_i);
    k_counts <<<gE, 256, 0, stream>>>(src_i, dst_i, deg_src, deg_dst, E);

    // forward rounds: gather src, segment by dst (deg_dst)
    k_scatter<<<gE, 256, 0, stream>>>(topic, src_i, dst_i, f1, E);
    k_div    <<<gN, 256, 0, stream>>>(f1, deg_dst, N);
    k_scatter<<<gE, 256, 0, stream>>>(f1, src_i, dst_i, f2, E);
    k_div    <<<gN, 256, 0, stream>>>(f2, deg_dst, N);
    // reverse rounds: gather dst, segment by src (deg_src)
    k_scatter<<<gE, 256, 0, stream>>>(topic, dst_i, src_i, r1, E);
    k_div    <<<gN, 256, 0, stream>>>(r1, deg_src, N);
    k_scatter<<<gE, 256, 0, stream>>>(r1, dst_i, src_i, r2, E);
    k_div    <<<gN, 256, 0, stream>>>(r2, deg_src, N);

    k_build<<<gN, 256, 0, stream>>>(x, topic, nte, f1, f2, r1, r2, h_e, N);

    k_gemm<<<(E + 511) / 512, 256, 0, stream>>>(q_emb, edge_attr, h_e, src_i, dst_i,
                                                W1, b1, W2, b2, out, E);
}

// Round 2
// 735.306 us; speedup vs baseline: 1.2969x; 1.2969x over previous
//
#include <hip/hip_runtime.h>
#include <cstdint>
#include <cstddef>

// N=50000 nodes, E=500000 edges, EMB=64, PRED_IN=276.
// Padded-K bf16 MFMA layout (K=288 = 9*32):
//   pk   0.. 63 : q_emb   (k 0..63)
//   pk  64..127 : edge_attr (k 138..201)
//   pk 128..201 : h_e[src] (k 64..137), pk 202..207 = 0
//   pk 208..281 : h_e[dst] (k 202..275), pk 282..287 = 0
// h_e stored bf16 [N][80]: x(64) topic(2) f1(2) f2(2) r1(2) r2(2) pad(6).

typedef __bf16 bf16x8 __attribute__((ext_vector_type(8)));
typedef unsigned short ushort8 __attribute__((ext_vector_type(8)));
typedef float f32x4 __attribute__((ext_vector_type(4)));

__device__ __forceinline__ unsigned int f2bf1(float f) {   // RNE fp32->bf16
    unsigned int u = __float_as_uint(f);
    return (u + 0x7fffu + ((u >> 16) & 1u)) >> 16;
}
__device__ __forceinline__ unsigned int pk2(float a, float b) {
    return f2bf1(a) | (f2bf1(b) << 16);
}
__device__ __forceinline__ bf16x8 cvt8(const float* __restrict__ p) {
    float4 v0 = *(const float4*)p;
    float4 v1 = *(const float4*)(p + 4);
    ushort8 s;
    s[0] = (unsigned short)f2bf1(v0.x); s[1] = (unsigned short)f2bf1(v0.y);
    s[2] = (unsigned short)f2bf1(v0.z); s[3] = (unsigned short)f2bf1(v0.w);
    s[4] = (unsigned short)f2bf1(v1.x); s[5] = (unsigned short)f2bf1(v1.y);
    s[6] = (unsigned short)f2bf1(v1.z); s[7] = (unsigned short)f2bf1(v1.w);
    return __builtin_bit_cast(bf16x8, s);
}

// ---------------------------------------------------------------------------
// Prep kernels
// ---------------------------------------------------------------------------

__global__ void k_detect(const int* __restrict__ idx, int E, int* __restrict__ flag) {
    int e = blockIdx.x * blockDim.x + threadIdx.x;
    bool nz = (e < E) && (idx[2 * e + 1] != 0);
    unsigned long long m = __ballot(nz);
    if (m != 0ull && (threadIdx.x & 63) == 0) atomicOr(flag, 1);
}

__global__ void k_convert(const int* __restrict__ idx, int E, const int* __restrict__ flag,
                          int* __restrict__ src_i, int* __restrict__ dst_i) {
    int e = blockIdx.x * blockDim.x + threadIdx.x;
    if (e >= E) return;
    if (*flag) { src_i[e] = idx[e];         dst_i[e] = idx[E + e]; }
    else       { src_i[e] = idx[2 * e];     dst_i[e] = idx[2 * E + 2 * e]; }
}

// counts + round-1 forward & reverse scatter, fused (6 atomics/edge)
__global__ void k_scat1(const int* __restrict__ src_i, const int* __restrict__ dst_i,
                        const float* __restrict__ topic,
                        float* __restrict__ deg_src, float* __restrict__ deg_dst,
                        float* __restrict__ f1, float* __restrict__ r1, int E) {
    int e = blockIdx.x * blockDim.x + threadIdx.x;
    if (e >= E) return;
    int s = src_i[e], d = dst_i[e];
    atomicAdd(&deg_dst[d], 1.0f);
    atomicAdd(&deg_src[s], 1.0f);
    float ts0 = topic[2 * s], ts1 = topic[2 * s + 1];
    float td0 = topic[2 * d], td1 = topic[2 * d + 1];
    atomicAdd(&f1[2 * d], ts0); atomicAdd(&f1[2 * d + 1], ts1);
    atomicAdd(&r1[2 * s], td0); atomicAdd(&r1[2 * s + 1], td1);
}

__global__ void k_div1(float* __restrict__ f1, float* __restrict__ r1,
                       const float* __restrict__ deg_src, const float* __restrict__ deg_dst, int N) {
    int n = blockIdx.x * blockDim.x + threadIdx.x;
    if (n >= N) return;
    float id = 1.0f / fmaxf(deg_dst[n], 1.0f);
    float is = 1.0f / fmaxf(deg_src[n], 1.0f);
    f1[2 * n] *= id; f1[2 * n + 1] *= id;
    r1[2 * n] *= is; r1[2 * n + 1] *= is;
}

// round-2 forward & reverse scatter, fused (4 atomics/edge)
__global__ void k_scat2(const int* __restrict__ src_i, const int* __restrict__ dst_i,
                        const float* __restrict__ f1, const float* __restrict__ r1,
                        float* __restrict__ f2, float* __restrict__ r2, int E) {
    int e = blockIdx.x * blockDim.x + threadIdx.x;
    if (e >= E) return;
    int s = src_i[e], d = dst_i[e];
    float a = f1[2 * s], b = f1[2 * s + 1];
    float c = r1[2 * d], dd = r1[2 * d + 1];
    atomicAdd(&f2[2 * d], a); atomicAdd(&f2[2 * d + 1], b);
    atomicAdd(&r2[2 * s], c); atomicAdd(&r2[2 * s + 1], dd);
}

// divide f2/r2 + build bf16 h_e row, fused
__global__ void k_build(const float* __restrict__ x, const float* __restrict__ topic,
                        const float* __restrict__ nte,
                        const float* __restrict__ f1, const float* __restrict__ f2,
                        const float* __restrict__ r1, const float* __restrict__ r2,
                        const float* __restrict__ deg_src, const float* __restrict__ deg_dst,
                        unsigned short* __restrict__ he, int N) {
    int n = blockIdx.x * blockDim.x + threadIdx.x;
    if (n >= N) return;
    const float4* xr = (const float4*)(x + (size_t)n * 64);
    float4 v[16];
    bool allz = true;
#pragma unroll
    for (int i = 0; i < 16; ++i) {
        v[i] = xr[i];
        allz = allz && (v[i].x == 0.f && v[i].y == 0.f && v[i].z == 0.f && v[i].w == 0.f);
    }
    const float4* nr = (const float4*)nte;
    unsigned int row[40];
#pragma unroll
    for (int i = 0; i < 16; ++i) {
        float4 s = allz ? nr[i] : v[i];
        row[2 * i]     = pk2(s.x, s.y);
        row[2 * i + 1] = pk2(s.z, s.w);
    }
    float idd = 1.0f / fmaxf(deg_dst[n], 1.0f);
    float ids = 1.0f / fmaxf(deg_src[n], 1.0f);
    row[32] = pk2(topic[2 * n], topic[2 * n + 1]);
    row[33] = pk2(f1[2 * n], f1[2 * n + 1]);
    row[34] = pk2(f2[2 * n] * idd, f2[2 * n + 1] * idd);
    row[35] = pk2(r1[2 * n], r1[2 * n + 1]);
    row[36] = pk2(r2[2 * n] * ids, r2[2 * n + 1] * ids);
    row[37] = 0u; row[38] = 0u; row[39] = 0u;
    uint4* dst = (uint4*)(he + (size_t)n * 80);
#pragma unroll
    for (int i = 0; i < 10; ++i) dst[i] = ((const uint4*)row)[i];
}

// padded bf16 W1^T [64 cols][288 pk]
__global__ void k_w1t(const float* __restrict__ W1, unsigned short* __restrict__ W1T) {
    int i = blockIdx.x * blockDim.x + threadIdx.x;
    if (i >= 64 * 288) return;
    int col = i / 288, pk = i - col * 288;
    int k = 0; bool valid = true;
    if (pk < 64)       { k = pk; }
    else if (pk < 128) { k = 138 + (pk - 64); }          // edge_attr
    else if (pk < 208) { int j = pk - 128; k = 64 + j;  valid = j < 74; }   // h_src
    else               { int j = pk - 208; k = 202 + j; valid = j < 74; }   // h_dst
    float v = valid ? W1[k * 64 + col] : 0.f;
    W1T[col * 288 + pk] = (unsigned short)f2bf1(v);
}

// ---------------------------------------------------------------------------
// MFMA edge-MLP: 64 edges/block, 4 waves, each wave 16 edges x 64 cols.
// ---------------------------------------------------------------------------

#define SAH 168   // h-row LDS stride in bf16 (80+80 packed + 8 pad)
#define SBW 296   // W1T LDS stride in bf16 (288 + 8 pad)

__launch_bounds__(256, 2)
__global__ void k_gemm(const float* __restrict__ q_emb,
                       const float* __restrict__ edge_attr,
                       const unsigned short* __restrict__ he,
                       const unsigned short* __restrict__ W1T,
                       const int* __restrict__ src_i, const int* __restrict__ dst_i,
                       const float* __restrict__ b1, const float* __restrict__ W2,
                       const float* __restrict__ b2, float* __restrict__ out, int E)
{
    __shared__ unsigned short sA[64 * SAH];  // h_src(80)||h_dst(80) per edge row
    __shared__ unsigned short sB[64 * SBW];  // W1T
    const int tid = threadIdx.x;
    const int e0  = blockIdx.x * 64;

    // stage W1T (L2-resident, 36 KB)
    for (int i = tid; i < 64 * 36; i += 256) {
        int col = i / 36, ch = i - col * 36;
        *(uint4*)&sB[col * SBW + ch * 8] = *(const uint4*)&W1T[col * 288 + ch * 8];
    }
    // stage gathered h_e rows (bf16, 160 B each)
    for (int i = tid; i < 64 * 10; i += 256) {
        int r = i / 10, ch = i - r * 10;
        int e = e0 + r; e = e < E ? e : E - 1;
        int node = src_i[e];
        *(uint4*)&sA[r * SAH + ch * 8] = *(const uint4*)&he[(size_t)node * 80 + ch * 8];
    }
    for (int i = tid; i < 64 * 10; i += 256) {
        int r = i / 10, ch = i - r * 10;
        int e = e0 + r; e = e < E ? e : E - 1;
        int node = dst_i[e];
        *(uint4*)&sA[r * SAH + 80 + ch * 8] = *(const uint4*)&he[(size_t)node * 80 + ch * 8];
    }

    const int w = tid >> 6, l = tid & 63, c = l & 15, q = l >> 4;
    int eM = e0 + w * 16 + c; eM = eM < E ? eM : E - 1;

    // A-fragments for ks 0..3 straight from global fp32 (coalesced full-row reads)
    bf16x8 aq0 = cvt8(q_emb     + (size_t)eM * 64 +      q * 8);
    bf16x8 aq1 = cvt8(q_emb     + (size_t)eM * 64 + 32 + q * 8);
    bf16x8 aa0 = cvt8(edge_attr + (size_t)eM * 64 +      q * 8);
    bf16x8 aa1 = cvt8(edge_attr + (size_t)eM * 64 + 32 + q * 8);

    __syncthreads();

    f32x4 acc0 = {0.f, 0.f, 0.f, 0.f};
    f32x4 acc1 = {0.f, 0.f, 0.f, 0.f};
    f32x4 acc2 = {0.f, 0.f, 0.f, 0.f};
    f32x4 acc3 = {0.f, 0.f, 0.f, 0.f};

    const unsigned short* ar = &sA[(w * 16 + c) * SAH + q * 8];
    const unsigned short* br = &sB[c * SBW + q * 8];

#define BFRAG(ct, ks) (*(const bf16x8*)(br + (ct) * 16 * SBW + (ks) * 32))
#define STEP(a_, ks)                                                              \
    acc0 = __builtin_amdgcn_mfma_f32_16x16x32_bf16(a_, BFRAG(0, ks), acc0, 0, 0, 0); \
    acc1 = __builtin_amdgcn_mfma_f32_16x16x32_bf16(a_, BFRAG(1, ks), acc1, 0, 0, 0); \
    acc2 = __builtin_amdgcn_mfma_f32_16x16x32_bf16(a_, BFRAG(2, ks), acc2, 0, 0, 0); \
    acc3 = __builtin_amdgcn_mfma_f32_16x16x32_bf16(a_, BFRAG(3, ks), acc3, 0, 0, 0);

    STEP(aq0, 0)
    STEP(aq1, 1)
    STEP(aa0, 2)
    STEP(aa1, 3)
#pragma unroll
    for (int ks = 4; ks < 9; ++ks) {
        bf16x8 a = *(const bf16x8*)(ar + (ks - 4) * 32);
        STEP(a, ks)
    }
#undef STEP
#undef BFRAG

    // epilogue: out[e] = b2 + sum_j relu(acc_j + b1_j) * W2_j
    float b1v0 = b1[c], b1v1 = b1[16 + c], b1v2 = b1[32 + c], b1v3 = b1[48 + c];
    float w2v0 = W2[c], w2v1 = W2[16 + c], w2v2 = W2[32 + c], w2v3 = W2[48 + c];
    float pr[4];
#pragma unroll
    for (int r = 0; r < 4; ++r) {
        float h0 = fmaxf(acc0[r] + b1v0, 0.f);
        float h1 = fmaxf(acc1[r] + b1v1, 0.f);
        float h2 = fmaxf(acc2[r] + b1v2, 0.f);
        float h3 = fmaxf(acc3[r] + b1v3, 0.f);
        float p = fmaf(h0, w2v0, fmaf(h1, w2v1, fmaf(h2, w2v2, h3 * w2v3)));
        p += __shfl_xor(p, 1);
        p += __shfl_xor(p, 2);
        p += __shfl_xor(p, 4);
        p += __shfl_xor(p, 8);
        pr[r] = p;
    }
    if (c == 0) {
        int eo = e0 + w * 16 + q * 4;     // E % 4 == 0, so eo < E => all 4 valid
        if (eo < E) {
            float bb = b2[0];
            float4 o = make_float4(pr[0] + bb, pr[1] + bb, pr[2] + bb, pr[3] + bb);
            *(float4*)&out[eo] = o;
        }
    }
}

// ---------------------------------------------------------------------------
// Launch
// ---------------------------------------------------------------------------

extern "C" void kernel_launch(void* const* d_in, const int* in_sizes, int n_in,
                              void* d_out, int out_size, void* d_ws, size_t ws_size,
                              hipStream_t stream)
{
    const float* x         = (const float*)d_in[0];
    const int*   eidx      = (const int*)  d_in[1];
    const float* edge_attr = (const float*)d_in[2];
    const float* topic     = (const float*)d_in[3];
    const float* q_emb     = (const float*)d_in[4];
    const float* nte       = (const float*)d_in[5];
    const float* W1        = (const float*)d_in[6];
    const float* b1        = (const float*)d_in[7];
    const float* W2        = (const float*)d_in[8];
    const float* b2        = (const float*)d_in[9];
    float* out = (float*)d_out;

    const int E = out_size;             // 500000
    const int N = in_sizes[0] / 64;     // 50000

    // Workspace: [flag 16][deg_src N][deg_dst N][f1 2N][f2 2N][r1 2N][r2 2N]
    //            [he bf16 80N][W1T bf16 64*288][src_i E][dst_i E]
    char* ws = (char*)d_ws;
    int*   flag    = (int*)ws;
    float* deg_src = (float*)(ws + 16);
    float* deg_dst = deg_src + N;
    float* f1  = deg_dst + N;
    float* f2  = f1 + 2 * (size_t)N;
    float* r1  = f2 + 2 * (size_t)N;
    float* r2  = r1 + 2 * (size_t)N;
    unsigned short* he  = (unsigned short*)(r2 + 2 * (size_t)N);
    unsigned short* W1T = he + (size_t)N * 80;
    int* src_i = (int*)(W1T + 64 * 288);
    int* dst_i = src_i + E;

    size_t needed = 16 + (size_t)40 * N + (size_t)160 * N + 64 * 288 * 2 + (size_t)8 * E;
    if (ws_size < needed) return;

    hipMemsetAsync(d_ws, 0, 16 + (size_t)40 * N, stream);   // flag + degs + f1/f2/r1/r2

    const int gE = (E + 255) / 256;
    const int gN = (N + 255) / 256;

    k_detect <<<gE, 256, 0, stream>>>(eidx, E, flag);
    k_convert<<<gE, 256, 0, stream>>>(eidx, E, flag, src_i, dst_i);
    k_scat1  <<<gE, 256, 0, stream>>>(src_i, dst_i, topic, deg_src, deg_dst, f1, r1, E);
    k_div1   <<<gN, 256, 0, stream>>>(f1, r1, deg_src, deg_dst, N);
    k_scat2  <<<gE, 256, 0, stream>>>(src_i, dst_i, f1, r1, f2, r2, E);
    k_build  <<<gN, 256, 0, stream>>>(x, topic, nte, f1, f2, r1, r2, deg_src, deg_dst, he, N);
    k_w1t    <<<(64 * 288 + 255) / 256, 256, 0, stream>>>(W1, W1T);

    k_gemm<<<(E + 63) / 64, 256, 0, stream>>>(q_emb, edge_attr, he, W1T,
                                              src_i, dst_i, b1, W2, b2, out, E);
}

// Round 3
// 599.714 us; speedup vs baseline: 1.5901x; 1.2261x over previous
//
#include <hip/hip_runtime.h>
#include <cstdint>
#include <cstddef>

// N=50000 nodes, E=500000 edges, EMB=64, PRED_IN=276.
// Padded-K bf16 MFMA layout (K=288 = 9*32):
//   pk   0.. 63 : q_emb     (k 0..63)
//   pk  64..127 : edge_attr (k 138..201)
//   pk 128..207 : h_e[src]  (k 64..137) + 6 pad
//   pk 208..287 : h_e[dst]  (k 202..275) + 6 pad
// h_e stored bf16 [N][80]: x(64) topic(2) f1(2) f2(2) r1(2) r2(2) pad(6).
//
// Prep uses a CSR build (2 int atomics/edge) instead of fp32 scatter-atomics
// (round-2 evidence: ~10 fp32 atomics/edge held prep at ~557us in both rounds).

typedef __bf16 bf16x8 __attribute__((ext_vector_type(8)));
typedef float f32x4 __attribute__((ext_vector_type(4)));

__device__ __forceinline__ unsigned int f2bf1(float f) {   // RNE fp32->bf16
    unsigned int u = __float_as_uint(f);
    return (u + 0x7fffu + ((u >> 16) & 1u)) >> 16;
}
__device__ __forceinline__ unsigned int pk2(float a, float b) {
    return f2bf1(a) | (f2bf1(b) << 16);
}
__device__ __forceinline__ bf16x8 cvt8(const float* __restrict__ p) {
    float4 v0 = *(const float4*)p;
    float4 v1 = *(const float4*)(p + 4);
    bf16x8 r;
    r[0] = (__bf16)v0.x; r[1] = (__bf16)v0.y; r[2] = (__bf16)v0.z; r[3] = (__bf16)v0.w;
    r[4] = (__bf16)v1.x; r[5] = (__bf16)v1.y; r[6] = (__bf16)v1.z; r[7] = (__bf16)v1.w;
    return r;
}

// ---------------------------------------------------------------------------
// Prep
// ---------------------------------------------------------------------------

__global__ void k_detect(const int* __restrict__ idx, int E, int* __restrict__ flag) {
    int e = blockIdx.x * blockDim.x + threadIdx.x;
    bool nz = (e < E) && (idx[2 * e + 1] != 0);
    unsigned long long m = __ballot(nz);
    if (m != 0ull && (threadIdx.x & 63) == 0) atomicOr(flag, 1);
}

// unpack indices + CSR slot assignment (the only atomics in prep: 2 int/edge)
__global__ void k_convert(const int* __restrict__ idx, int E, const int* __restrict__ flag,
                          int* __restrict__ src_i, int* __restrict__ dst_i,
                          int* __restrict__ cnt_dst, int* __restrict__ cnt_src,
                          unsigned short* __restrict__ pos_f, unsigned short* __restrict__ pos_r) {
    int e = blockIdx.x * blockDim.x + threadIdx.x;
    if (e >= E) return;
    int s, d;
    if (*flag) { s = idx[e];     d = idx[E + e]; }
    else       { s = idx[2 * e]; d = idx[2 * E + 2 * e]; }
    src_i[e] = s; dst_i[e] = d;
    pos_f[e] = (unsigned short)atomicAdd(&cnt_dst[d], 1);
    pos_r[e] = (unsigned short)atomicAdd(&cnt_src[s], 1);
}

// exclusive scan of cnt -> off; block 0: cnt_dst->off_f, block 1: cnt_src->off_r
__global__ void k_scan(const int* __restrict__ cnt_dst, const int* __restrict__ cnt_src,
                       int* __restrict__ off_f, int* __restrict__ off_r, int N) {
    const int* cnt = (blockIdx.x == 0) ? cnt_dst : cnt_src;
    int* off       = (blockIdx.x == 0) ? off_f   : off_r;
    const int t = threadIdx.x;                 // 1024 threads
    const int C = (N + 1023) / 1024;
    int lo = t * C, hi = lo + C; if (hi > N) hi = N; if (lo > N) lo = N;
    int sum = 0;
    for (int i = lo; i < hi; ++i) sum += cnt[i];
    __shared__ int wsum[16];
    int lane = t & 63, wv = t >> 6;
    int v = sum;
    for (int ofs = 1; ofs < 64; ofs <<= 1) {
        int u = __shfl_up(v, ofs);
        if (lane >= ofs) v += u;
    }
    if (lane == 63) wsum[wv] = v;
    __syncthreads();
    if (wv == 0) {
        int x = (lane < 16) ? wsum[lane] : 0;
        for (int ofs = 1; ofs < 16; ofs <<= 1) {
            int u = __shfl_up(x, ofs);
            if (lane >= ofs) x += u;
        }
        if (lane < 16) wsum[lane] = x;
    }
    __syncthreads();
    int base = (wv > 0 ? wsum[wv - 1] : 0) + (v - sum);
    for (int i = lo; i < hi; ++i) { off[i] = base; base += cnt[i]; }
}

__global__ void k_fill(const int* __restrict__ src_i, const int* __restrict__ dst_i,
                       const unsigned short* __restrict__ pos_f, const unsigned short* __restrict__ pos_r,
                       const int* __restrict__ off_f, const int* __restrict__ off_r,
                       int* __restrict__ csr_f, int* __restrict__ csr_r, int E) {
    int e = blockIdx.x * blockDim.x + threadIdx.x;
    if (e >= E) return;
    int s = src_i[e], d = dst_i[e];
    csr_f[off_f[d] + pos_f[e]] = s;
    csr_r[off_r[s] + pos_r[e]] = d;
}

// atomic-free segment means (normalized at write)
__global__ void k_round(const int* __restrict__ off_f, const int* __restrict__ csr_f,
                        const int* __restrict__ off_r, const int* __restrict__ csr_r,
                        const float* __restrict__ hf_in,   // gathered for forward
                        const float* __restrict__ hr_in,   // gathered for reverse
                        float* __restrict__ f_out, float* __restrict__ r_out,
                        int N, int E) {
    int n = blockIdx.x * blockDim.x + threadIdx.x;
    if (n >= N) return;
    const float2* hf = (const float2*)hf_in;
    const float2* hr = (const float2*)hr_in;
    {
        int b = off_f[n], e = (n + 1 < N) ? off_f[n + 1] : E;
        float sx = 0.f, sy = 0.f;
        for (int j = b; j < e; ++j) { float2 t = hf[csr_f[j]]; sx += t.x; sy += t.y; }
        float inv = 1.0f / (float)max(e - b, 1);
        ((float2*)f_out)[n] = make_float2(sx * inv, sy * inv);
    }
    {
        int b = off_r[n], e = (n + 1 < N) ? off_r[n + 1] : E;
        float sx = 0.f, sy = 0.f;
        for (int j = b; j < e; ++j) { float2 t = hr[csr_r[j]]; sx += t.x; sy += t.y; }
        float inv = 1.0f / (float)max(e - b, 1);
        ((float2*)r_out)[n] = make_float2(sx * inv, sy * inv);
    }
}

// build bf16 h_e row (all feature buffers pre-normalized)
__global__ void k_build(const float* __restrict__ x, const float* __restrict__ topic,
                        const float* __restrict__ nte,
                        const float* __restrict__ f1, const float* __restrict__ f2,
                        const float* __restrict__ r1, const float* __restrict__ r2,
                        unsigned short* __restrict__ he, int N) {
    int n = blockIdx.x * blockDim.x + threadIdx.x;
    if (n >= N) return;
    const float4* xr = (const float4*)(x + (size_t)n * 64);
    float4 v[16];
    bool allz = true;
#pragma unroll
    for (int i = 0; i < 16; ++i) {
        v[i] = xr[i];
        allz = allz && (v[i].x == 0.f && v[i].y == 0.f && v[i].z == 0.f && v[i].w == 0.f);
    }
    const float4* nr = (const float4*)nte;
    unsigned int row[40];
#pragma unroll
    for (int i = 0; i < 16; ++i) {
        float4 s = allz ? nr[i] : v[i];
        row[2 * i]     = pk2(s.x, s.y);
        row[2 * i + 1] = pk2(s.z, s.w);
    }
    row[32] = pk2(topic[2 * n], topic[2 * n + 1]);
    row[33] = pk2(f1[2 * n], f1[2 * n + 1]);
    row[34] = pk2(f2[2 * n], f2[2 * n + 1]);
    row[35] = pk2(r1[2 * n], r1[2 * n + 1]);
    row[36] = pk2(r2[2 * n], r2[2 * n + 1]);
    row[37] = 0u; row[38] = 0u; row[39] = 0u;
    uint4* dst = (uint4*)(he + (size_t)n * 80);
#pragma unroll
    for (int i = 0; i < 10; ++i) dst[i] = ((const uint4*)row)[i];
}

// padded bf16 W1^T [64 cols][288 pk]
__global__ void k_w1t(const float* __restrict__ W1, unsigned short* __restrict__ W1T) {
    int i = blockIdx.x * blockDim.x + threadIdx.x;
    if (i >= 64 * 288) return;
    int col = i / 288, pk = i - col * 288;
    int k = 0; bool valid = true;
    if (pk < 64)       { k = pk; }
    else if (pk < 128) { k = 138 + (pk - 64); }
    else if (pk < 208) { int j = pk - 128; k = 64 + j;  valid = j < 74; }
    else               { int j = pk - 208; k = 202 + j; valid = j < 74; }
    float v = valid ? W1[k * 64 + col] : 0.f;
    W1T[col * 288 + pk] = (unsigned short)f2bf1(v);
}

// ---------------------------------------------------------------------------
// MFMA edge-MLP, LDS-free: 256 edges/block, 4 waves, 64 edges/wave (4 M-tiles).
// B frags read from L2-resident W1T; he frags gathered per-lane from global.
// ks-outer loop: each B frag read once per wave.
// ---------------------------------------------------------------------------

__launch_bounds__(256, 3)
__global__ void k_gemm(const float* __restrict__ q_emb,
                       const float* __restrict__ edge_attr,
                       const unsigned short* __restrict__ he,
                       const unsigned short* __restrict__ W1T,
                       const int* __restrict__ src_i, const int* __restrict__ dst_i,
                       const float* __restrict__ b1, const float* __restrict__ W2,
                       const float* __restrict__ b2, float* __restrict__ out, int E)
{
    const int tid = threadIdx.x;
    const int w = tid >> 6, l = tid & 63, c = l & 15, q = l >> 4;
    const int ebase = blockIdx.x * 256 + w * 64;

    const float* gq[4];
    const float* ga[4];
    const unsigned short* hs[4];
    const unsigned short* hd[4];
#pragma unroll
    for (int t = 0; t < 4; ++t) {
        int ee = ebase + t * 16 + c; ee = ee < E ? ee : E - 1;
        int s = src_i[ee], d = dst_i[ee];
        gq[t] = q_emb     + (size_t)ee * 64 + q * 8;
        ga[t] = edge_attr + (size_t)ee * 64 + q * 8;
        hs[t] = he + (size_t)s * 80 + q * 8;
        hd[t] = he + (size_t)d * 80 + q * 8;
    }

    float b1v[4], w2v[4];
#pragma unroll
    for (int ct = 0; ct < 4; ++ct) { b1v[ct] = b1[ct * 16 + c]; w2v[ct] = W2[ct * 16 + c]; }
    const float bb = b2[0];

    f32x4 acc[4][4] = {};   // [tile][ct]

    const unsigned short* wrow = W1T + (size_t)c * 288 + q * 8;
#define BF(ct, ks) (*(const bf16x8*)(wrow + (ct) * (16 * 288) + (ks) * 32))
#define KSTEP(ks, AEXPR)                                                               \
    {                                                                                  \
        bf16x8 bf0 = BF(0, ks), bf1 = BF(1, ks), bf2 = BF(2, ks), bf3 = BF(3, ks);     \
        _Pragma("unroll")                                                              \
        for (int t = 0; t < 4; ++t) {                                                  \
            bf16x8 a = (AEXPR);                                                        \
            acc[t][0] = __builtin_amdgcn_mfma_f32_16x16x32_bf16(a, bf0, acc[t][0], 0, 0, 0); \
            acc[t][1] = __builtin_amdgcn_mfma_f32_16x16x32_bf16(a, bf1, acc[t][1], 0, 0, 0); \
            acc[t][2] = __builtin_amdgcn_mfma_f32_16x16x32_bf16(a, bf2, acc[t][2], 0, 0, 0); \
            acc[t][3] = __builtin_amdgcn_mfma_f32_16x16x32_bf16(a, bf3, acc[t][3], 0, 0, 0); \
        }                                                                              \
    }

    KSTEP(0, cvt8(gq[t]))
    KSTEP(1, cvt8(gq[t] + 32))
    KSTEP(2, cvt8(ga[t]))
    KSTEP(3, cvt8(ga[t] + 32))
    KSTEP(4, (*(const bf16x8*)(hs[t])))
    KSTEP(5, (*(const bf16x8*)(hs[t] + 32)))
    KSTEP(6, (*(const bf16x8*)((q < 2) ? (hs[t] + 64) : (hd[t] - 16))))
    KSTEP(7, (*(const bf16x8*)(hd[t] + 16)))
    KSTEP(8, (*(const bf16x8*)(hd[t] + 48)))
#undef KSTEP
#undef BF

#pragma unroll
    for (int t = 0; t < 4; ++t) {
        float pr[4];
#pragma unroll
        for (int r = 0; r < 4; ++r) {
            float h0 = fmaxf(acc[t][0][r] + b1v[0], 0.f);
            float h1 = fmaxf(acc[t][1][r] + b1v[1], 0.f);
            float h2 = fmaxf(acc[t][2][r] + b1v[2], 0.f);
            float h3 = fmaxf(acc[t][3][r] + b1v[3], 0.f);
            float p = fmaf(h0, w2v[0], fmaf(h1, w2v[1], fmaf(h2, w2v[2], h3 * w2v[3])));
            p += __shfl_xor(p, 1);
            p += __shfl_xor(p, 2);
            p += __shfl_xor(p, 4);
            p += __shfl_xor(p, 8);
            pr[r] = p;
        }
        if (c == 0) {
            int eo = ebase + t * 16 + q * 4;     // E % 16 == 0: tile fully valid or fully out
            if (eo < E) {
                float4 o = make_float4(pr[0] + bb, pr[1] + bb, pr[2] + bb, pr[3] + bb);
                *(float4*)&out[eo] = o;
            }
        }
    }
}

// ---------------------------------------------------------------------------
// Launch
// ---------------------------------------------------------------------------

extern "C" void kernel_launch(void* const* d_in, const int* in_sizes, int n_in,
                              void* d_out, int out_size, void* d_ws, size_t ws_size,
                              hipStream_t stream)
{
    const float* x         = (const float*)d_in[0];
    const int*   eidx      = (const int*)  d_in[1];
    const float* edge_attr = (const float*)d_in[2];
    const float* topic     = (const float*)d_in[3];
    const float* q_emb     = (const float*)d_in[4];
    const float* nte       = (const float*)d_in[5];
    const float* W1        = (const float*)d_in[6];
    const float* b1        = (const float*)d_in[7];
    const float* W2        = (const float*)d_in[8];
    const float* b2        = (const float*)d_in[9];
    float* out = (float*)d_out;

    const int E = out_size;             // 500000
    const int N = in_sizes[0] / 64;     // 50000

    // Workspace (aliased; total == 14,036,880 B, same as round-2 which fit):
    // [flag 16][src_i 4E][dst_i 4E][off_f 4N][off_r 4N]
    // [fblk: f1 2N | f2 2N | r1 2N | r2 2N floats]  (cnt_dst/cnt_src alias f1's ints)
    // [heblk: max(he 160N B, pos_f 2E + pos_r 2E + csr_f 4E + csr_r 4E B)]
    // [W1T 64*288*2]
    char* ws = (char*)d_ws;
    int* flag  = (int*)ws;
    int* src_i = (int*)(ws + 16);
    int* dst_i = src_i + E;
    int* off_f = dst_i + E;
    int* off_r = off_f + N;
    float* fblk = (float*)(off_r + N);
    float* f1 = fblk;
    float* f2 = fblk + 2 * (size_t)N;
    float* r1 = fblk + 4 * (size_t)N;
    float* r2 = fblk + 6 * (size_t)N;
    int* cnt_dst = (int*)f1;            // dead before f1 is written
    int* cnt_src = cnt_dst + N;
    char* heblk = (char*)(fblk + 8 * (size_t)N);
    unsigned short* pos_f = (unsigned short*)heblk;          // dead before he is written
    unsigned short* pos_r = pos_f + E;
    int* csr_f = (int*)(pos_r + E);
    int* csr_r = csr_f + E;
    unsigned short* he = (unsigned short*)heblk;
    size_t he_bytes = (size_t)N * 160;
    size_t trans_bytes = (size_t)E * 12;
    size_t heblk_bytes = he_bytes > trans_bytes ? he_bytes : trans_bytes;
    unsigned short* W1T = (unsigned short*)(heblk + heblk_bytes);

    size_t needed = 16 + (size_t)8 * E + (size_t)8 * N + (size_t)32 * N + heblk_bytes + 64 * 288 * 2;
    if (ws_size < needed) return;

    hipMemsetAsync(flag, 0, 16, stream);
    hipMemsetAsync(cnt_dst, 0, (size_t)8 * N, stream);   // both cnt arrays

    const int gE = (E + 255) / 256;
    const int gN = (N + 255) / 256;

    k_detect <<<gE, 256, 0, stream>>>(eidx, E, flag);
    k_convert<<<gE, 256, 0, stream>>>(eidx, E, flag, src_i, dst_i,
                                      cnt_dst, cnt_src, pos_f, pos_r);
    k_scan   <<<2, 1024, 0, stream>>>(cnt_dst, cnt_src, off_f, off_r, N);
    k_fill   <<<gE, 256, 0, stream>>>(src_i, dst_i, pos_f, pos_r, off_f, off_r,
                                      csr_f, csr_r, E);
    k_round  <<<gN, 256, 0, stream>>>(off_f, csr_f, off_r, csr_r, topic, topic, f1, r1, N, E);
    k_round  <<<gN, 256, 0, stream>>>(off_f, csr_f, off_r, csr_r, f1, r1, f2, r2, N, E);
    k_build  <<<gN, 256, 0, stream>>>(x, topic, nte, f1, f2, r1, r2, he, N);
    k_w1t    <<<(64 * 288 + 255) / 256, 256, 0, stream>>>(W1, W1T);

    k_gemm<<<(E + 255) / 256, 256, 0, stream>>>(q_emb, edge_attr, he, W1T,
                                                src_i, dst_i, b1, W2, b2, out, E);
}